// Round 8
// baseline (309.922 us; speedup 1.0000x reference)
//
#include <hip/hip_runtime.h>
#include <hip/hip_bf16.h>

// MHA forward: b=2, t=2048, d=1024, h=16, n=64. Inputs/outputs FLOAT32.
// bf16 internals. ws (u16, 58.7 MB, proven): kb|qb|vb (4194304 ea) |
// Wkb|Wqb|Wvb|Wob (1048576 ea) | Kp|Qp|Vt (4194304 ea) | Op aliases kb.
// GEMMs: single-barrier double-buffered global_load_lds K-loop.
// attn: 8-wave blocks (q-half x s-slice), barrier-free main loop, raw v_exp.

typedef unsigned short u16;
typedef unsigned int   u32;
using short8 = __attribute__((ext_vector_type(8))) short;
using f32x4  = __attribute__((ext_vector_type(4))) float;

__device__ __forceinline__ u16 f2b(float f) {
    u32 u = __float_as_uint(f);
    u += 0x7FFFu + ((u >> 16) & 1u);
    return (u16)(u >> 16);
}
__device__ __forceinline__ u32 pack2(float lo, float hi) {
    union { __hip_bfloat162 h; u32 u; } c;
    c.h = __float22bfloat162_rn(make_float2(lo, hi));
    return c.u;
}
__device__ __forceinline__ float fexp2(float x) {
    return __builtin_amdgcn_exp2f(x);
}
__device__ __forceinline__ void gld_lds16(const u16* g, u16* l) {
    __builtin_amdgcn_global_load_lds(
        (const __attribute__((address_space(1))) void*)g,
        (__attribute__((address_space(3))) void*)l, 16, 0, 0);
}

// ---------------------------------------------------------------------------
// fp32 -> bf16 convert. grid (1024, 7).
// ---------------------------------------------------------------------------
__global__ __launch_bounds__(256) void convert_kernel(
    const float* s0, const float* s1, const float* s2, const float* s3,
    const float* s4, const float* s5, const float* s6,
    u16* d0, u16* d1, u16* d2, u16* d3, u16* d4, u16* d5, u16* d6)
{
    const int y = blockIdx.y;
    const float* s; u16* d; u32 n;
    switch (y) {
        case 0: s = s0; d = d0; n = 1048576; break;
        case 1: s = s1; d = d1; n = 1048576; break;
        case 2: s = s2; d = d2; n = 1048576; break;
        case 3: s = s3; d = d3; n = 262144; break;
        case 4: s = s4; d = d4; n = 262144; break;
        case 5: s = s5; d = d5; n = 262144; break;
        default: s = s6; d = d6; n = 262144; break;
    }
    for (u32 i = blockIdx.x * 256 + threadIdx.x; i < n; i += 256 * 1024) {
        float4 f = ((const float4*)s)[i];
        uint2 o; o.x = pack2(f.x, f.y); o.y = pack2(f.z, f.w);
        ((uint2*)d)[i] = o;
    }
}

// ---------------------------------------------------------------------------
// GEMM core: C(128x128 tile) = A[m][k] @ B[n][k]^T, K=1024, bf16.
// Single-barrier DOUBLE-BUFFERED global_load_lds K-loop: loads for iter i+1
// issued right after barrier i, drained by compiler's vmcnt(0) at barrier
// i+1 — a full compute phase overlaps each load batch.
// MODE 0: u16 C row-major N=1024. MODE 2: f32 C row-major + bias.
// MODE 3: u16 C in Vt layout (coalesced).
// ---------------------------------------------------------------------------
template <int MODE>
__device__ __forceinline__ void gemm_core(
    const u16* __restrict__ A, const u16* __restrict__ B,
    void* __restrict__ C, const float* __restrict__ bias, float scale,
    u32 bm, u32 bn)
{
    constexpr u32 K = 1024;
    __shared__ u16 As[2][4096];
    __shared__ u16 Bs[2][4096];

    const int tid  = threadIdx.x;
    const int lane = tid & 63;
    const int w    = tid >> 6;
    const int wr   = w >> 1, wc = w & 1;
    const int ml   = lane & 15, g = lane >> 4;

    f32x4 acc[4][4] = {};

    const u32 srow = w * 32 + (lane >> 2);
    const u32 scol = (u32)(((lane & 3) ^ ((lane >> 3) & 3)) * 8);
    const u16* gA = A + (size_t)(bm + srow) * K + scol;
    const u16* gB = B + (size_t)(bn + srow) * K + scol;
    const u32 lo = (u32)(w * 1024);
    const u32 fsw = (u32)((g ^ ((ml >> 1) & 3)) * 8);

    // prologue: stage iter 0 into buffer 0
    gld_lds16(gA,          &As[0][lo]);
    gld_lds16(gA + 16 * K, &As[0][lo + 512]);
    gld_lds16(gB,          &Bs[0][lo]);
    gld_lds16(gB + 16 * K, &Bs[0][lo + 512]);

    for (u32 i = 0; i < 32; ++i) {
        __syncthreads();                       // drains buf-p loads (overlapped)
        const u32 p = i & 1;
        if (i + 1 < 32) {
            const u32 kk = (i + 1) * 32;
            const u32 np = p ^ 1;
            gld_lds16(gA + kk,          &As[np][lo]);
            gld_lds16(gA + 16 * K + kk, &As[np][lo + 512]);
            gld_lds16(gB + kk,          &Bs[np][lo]);
            gld_lds16(gB + 16 * K + kk, &Bs[np][lo + 512]);
        }

        short8 af[4], bf[4];
#pragma unroll
        for (int it = 0; it < 4; ++it)
            af[it] = *(const short8*)&As[p][(wr * 64 + it * 16 + ml) * 32 + fsw];
#pragma unroll
        for (int ct = 0; ct < 4; ++ct)
            bf[ct] = *(const short8*)&Bs[p][(wc * 64 + ct * 16 + ml) * 32 + fsw];
#pragma unroll
        for (int it = 0; it < 4; ++it)
#pragma unroll
            for (int ct = 0; ct < 4; ++ct)
                acc[it][ct] = __builtin_amdgcn_mfma_f32_16x16x32_bf16(
                    af[it], bf[ct], acc[it][ct], 0, 0, 0);
    }

    if (MODE == 3) {
#pragma unroll
        for (int ct = 0; ct < 4; ++ct) {
            const u32 col = bn + wc * 64 + ct * 16 + ml;
            u16* dst = (u16*)C + (col >> 11) * 2097152 + (col & 2047);
#pragma unroll
            for (int it = 0; it < 4; ++it) {
                const u32 row = bm + wr * 64 + it * 16 + g * 4;
#pragma unroll
                for (int r = 0; r < 4; ++r)
                    dst[(size_t)(row + r) * 2048] = f2b(acc[it][ct][r]);
            }
        }
    } else {
#pragma unroll
        for (int ct = 0; ct < 4; ++ct) {
            const u32 col = bn + wc * 64 + ct * 16 + ml;
            const float bv = (MODE == 2 && bias) ? bias[col] : 0.0f;
#pragma unroll
            for (int it = 0; it < 4; ++it) {
                const u32 row = bm + wr * 64 + it * 16 + g * 4;
#pragma unroll
                for (int r = 0; r < 4; ++r) {
                    const float v = acc[it][ct][r] * scale + bv;
                    if (MODE == 2) ((float*)C)[(size_t)(row + r) * 1024 + col] = v;
                    else           ((u16*)C)[(size_t)(row + r) * 1024 + col] = f2b(v);
                }
            }
        }
    }
}

// z=0: Kp = kb@Wk^T ; z=1: Qp = qb@Wq^T * 0.125*log2e ; z=2: Vt = Wv @ v^T
__global__ __launch_bounds__(256) void proj3_kernel(
    const u16* kb, const u16* qb, const u16* vb,
    const u16* Wkb, const u16* Wqb, const u16* Wvb,
    u16* Kp, u16* Qp, u16* Vt)
{
    if (blockIdx.z == 0)
        gemm_core<0>(kb, Wkb, Kp, nullptr, 1.0f, blockIdx.y * 128, blockIdx.x * 128);
    else if (blockIdx.z == 1)
        gemm_core<0>(qb, Wqb, Qp, nullptr, 0.18033688011112042f, blockIdx.y * 128, blockIdx.x * 128);
    else
        gemm_core<3>(Wvb, vb, Vt, nullptr, 1.0f, blockIdx.x * 128, blockIdx.y * 128);
}

__global__ __launch_bounds__(256) void out_gemm_kernel(
    const u16* A, const u16* W, float* C, const float* bias)
{
    gemm_core<2>(A, W, C, bias, 1.0f, blockIdx.y * 128, blockIdx.x * 128);
}

// ---------------------------------------------------------------------------
// Flash attention v5: 512 threads / 8 waves. wave = (q-half qh of 32 q,
// s-slice sl of 32 s per 128-s iter). Barrier-free main loop; K/V/Q frags
// direct from global; per-wave swizzled P strip (32q x 32s) in LDS.
// oacc[4][2] = 32 AGPR; __launch_bounds__(512,4) caps regs for 4 waves/SIMD.
// Cross-wave O/l reduction over the 4 s-slices at the end.
// ---------------------------------------------------------------------------
__global__ __launch_bounds__(512, 4) void attn_kernel(
    const u16* __restrict__ Qp, const u16* __restrict__ Kp,
    const u16* __restrict__ Vt, u16* __restrict__ Op)
{
    __shared__ u16   Ps[8 * 1024];    // 8 wave strips x (32q x 32s), 16 KB
    __shared__ float Rr[4096];        // reduce buffer A (2 q-halves), 16 KB
    __shared__ float Lr[256];         // 4 slices x 64 q

    const int tid  = threadIdx.x;
    const int lane = tid & 63;
    const int wv   = tid >> 6;        // 0..7
    const int sl   = wv >> 1;         // s-slice 0..3
    const int qh   = wv & 1;          // q-half 0..1
    const int ml   = lane & 15;
    const int g    = lane >> 4;
    const u32 bh   = blockIdx.y;
    const u32 b    = bh >> 4, h = bh & 15;
    const u32 t0   = blockIdx.x * 64;

    const u32 base  = b * 2048 * 1024 + h * 64;
    const u32 vbase = bh * 64 * 2048;

    // Q B-frags: B[k=d][n=q], lane q = qh*32 + qt*16 + ml
    short8 bq[2][2];
#pragma unroll
    for (int qt = 0; qt < 2; ++qt) {
        const u16* qr = Qp + base + (t0 + qh * 32 + qt * 16 + ml) * 1024 + g * 8;
        bq[qt][0] = *(const short8*)qr;
        bq[qt][1] = *(const short8*)(qr + 32);
    }

    f32x4 oacc[4][2] = {};            // [dt][qt]: O^T[d=dt*16+g*4+r][q]
    float l2a[2] = {};

    u16* Pw = &Ps[wv * 1024];
    u32* Pw32 = (u32*)Pw;

    u32 kOff = base + (sl * 32 + ml) * 1024 + g * 8;   // += 128*1024 per iter
    u32 vOff = vbase + ml * 2048 + sl * 32 + g * 8;    // += 128 per iter

    for (int it = 0; it < 16; ++it) {
        // V A-frags: A[m=d=dt*16+ml][k=s_local]
        short8 va[4];
#pragma unroll
        for (int dt = 0; dt < 4; ++dt)
            va[dt] = *(const short8*)(Vt + vOff + dt * 16 * 2048);

        // QK: two 16-s sub-tiles of this wave's 32-s slice
#pragma unroll
        for (int sub = 0; sub < 2; ++sub) {
            const u16* kp = Kp + kOff + sub * 16 * 1024;
            short8 ka0 = *(const short8*)kp;
            short8 ka1 = *(const short8*)(kp + 32);
            const u32 ch = (u32)(sub * 2 + (g >> 1));
#pragma unroll
            for (int qt = 0; qt < 2; ++qt) {
                f32x4 z = {};
                z = __builtin_amdgcn_mfma_f32_16x16x32_bf16(ka0, bq[qt][0], z, 0, 0, 0);
                z = __builtin_amdgcn_mfma_f32_16x16x32_bf16(ka1, bq[qt][1], z, 0, 0, 0);
                const float p0 = fexp2(z[0]), p1 = fexp2(z[1]);
                const float p2 = fexp2(z[2]), p3 = fexp2(z[3]);
                l2a[qt] += (p0 + p1) + (p2 + p3);
                const u32 q = (u32)(qt * 16 + ml);
                const u32 idx = q * 16 + ((ch ^ ((q >> 1) & 3)) << 2) + (g & 1) * 2;
                uint2 pv; pv.x = pack2(p0, p1); pv.y = pack2(p2, p3);
                *(uint2*)&Pw32[idx] = pv;
            }
        }
        kOff += 128 * 1024;
        vOff += 128;

        // P B-frags (same-wave RAW through LDS; compiler inserts lgkmcnt)
        short8 pb[2];
#pragma unroll
        for (int qt = 0; qt < 2; ++qt) {
            const u32 q = (u32)(qt * 16 + ml);
            pb[qt] = *(const short8*)&Pw[q * 32 + ((g ^ ((q >> 1) & 3)) * 8)];
        }
#pragma unroll
        for (int dt = 0; dt < 4; ++dt)
#pragma unroll
            for (int qt = 0; qt < 2; ++qt)
                oacc[dt][qt] = __builtin_amdgcn_mfma_f32_16x16x32_bf16(
                    va[dt], pb[qt], oacc[dt][qt], 0, 0, 0);
    }

    // ---- reductions (only barriers in the kernel) ----
#pragma unroll
    for (int qt = 0; qt < 2; ++qt) {
        l2a[qt] += __shfl_xor(l2a[qt], 16);
        l2a[qt] += __shfl_xor(l2a[qt], 32);
        if (g == 0) Lr[sl * 64 + qh * 32 + qt * 16 + ml] = l2a[qt];
    }
    __syncthreads();                  // l published; P strips now reusable

    float* RA = Rr + qh * 2048;       // [d_local 0..63][q_local 0..31]
    float* RB = (float*)Ps + qh * 2048;

#define WRITE_R(Rp)                                                          \
    {_Pragma("unroll") for (int dt = 0; dt < 4; ++dt)                        \
     _Pragma("unroll") for (int qt = 0; qt < 2; ++qt)                        \
     _Pragma("unroll") for (int r = 0; r < 4; ++r)                           \
        (Rp)[(dt * 16 + g * 4 + r) * 32 + qt * 16 + ml] = oacc[dt][qt][r];}
#define ADD_R(Rp)                                                            \
    {_Pragma("unroll") for (int dt = 0; dt < 4; ++dt)                        \
     _Pragma("unroll") for (int qt = 0; qt < 2; ++qt)                        \
     _Pragma("unroll") for (int r = 0; r < 4; ++r)                           \
        oacc[dt][qt][r] += (Rp)[(dt * 16 + g * 4 + r) * 32 + qt * 16 + ml];}

    if (sl == 1) WRITE_R(RA)
    if (sl == 3) WRITE_R(RB)
    __syncthreads();
    if (sl == 0) ADD_R(RA)
    if (sl == 2) ADD_R(RB)
    __syncthreads();
    if (sl == 2) WRITE_R(RA)
    __syncthreads();
    if (sl == 0) {
        ADD_R(RA)
#pragma unroll
        for (int qt = 0; qt < 2; ++qt) {
            const u32 qi = (u32)(qh * 32 + qt * 16 + ml);
            const float inv = 1.0f /
                (Lr[qi] + Lr[64 + qi] + Lr[128 + qi] + Lr[192 + qi]);
            const u32 row = (b * 2048 + t0 + qi) * 1024 + h * 64;
#pragma unroll
            for (int dt = 0; dt < 4; ++dt) {
                const u32 ci = row + dt * 16 + g * 4;
                *(u32*)&Op[ci]     = pack2(oacc[dt][qt][0] * inv, oacc[dt][qt][1] * inv);
                *(u32*)&Op[ci + 2] = pack2(oacc[dt][qt][2] * inv, oacc[dt][qt][3] * inv);
            }
        }
    }
#undef WRITE_R
#undef ADD_R
}

extern "C" void kernel_launch(void* const* d_in, const int* in_sizes, int n_in,
                              void* d_out, int out_size, void* d_ws, size_t ws_size,
                              hipStream_t stream)
{
    const float* kin = (const float*)d_in[0];
    const float* qin = (const float*)d_in[1];
    const float* vin = (const float*)d_in[2];
    const float* Wk  = (const float*)d_in[3];
    const float* Wq  = (const float*)d_in[4];
    const float* Wv  = (const float*)d_in[5];
    const float* Wo  = (const float*)d_in[6];
    const float* bo  = (const float*)d_in[7];
    float* out = (float*)d_out;

    const size_t ACT = 4194304;
    const size_t WSZ = 1048576;

    u16* kb  = (u16*)d_ws;
    u16* qb  = kb + ACT;
    u16* vb  = qb + ACT;
    u16* Wkb = vb + ACT;
    u16* Wqb = Wkb + WSZ;
    u16* Wvb = Wqb + WSZ;
    u16* Wob = Wvb + WSZ;
    u16* Kp  = Wob + WSZ;
    u16* Qp  = Kp + ACT;
    u16* Vt  = Qp + ACT;
    u16* Op  = kb;   // alias: kb consumed by proj3 before attn writes Op

    convert_kernel<<<dim3(1024, 7), 256, 0, stream>>>(
        kin, qin, vin, Wk, Wq, Wv, Wo, kb, qb, vb, Wkb, Wqb, Wvb, Wob);
    proj3_kernel<<<dim3(8, 32, 3), 256, 0, stream>>>(
        kb, qb, vb, Wkb, Wqb, Wvb, Kp, Qp, Vt);
    attn_kernel<<<dim3(32, 32), 512, 0, stream>>>(Qp, Kp, Vt, Op);
    out_gemm_kernel<<<dim3(8, 32), 256, 0, stream>>>(Op, Wob, out, bo);
}

// Round 9
// 229.575 us; speedup vs baseline: 1.3500x; 1.3500x over previous
//
#include <hip/hip_runtime.h>
#include <hip/hip_bf16.h>

// MHA forward: b=2, t=2048, d=1024, h=16, n=64. Inputs/outputs FLOAT32.
// bf16 internals. ws (u16, 58.7 MB, proven): kb|qb|vb (4194304 ea) |
// Wkb|Wqb|Wvb|Wob (1048576 ea) | Kp|Qp|Vt (4194304 ea) | Op aliases kb.
// GEMMs: round-7 2-barrier global_load_lds K-loop (proven 162 us non-attn);
// out_gemm uses 64x128 tiles (512 blocks = 2/CU). attn: round-7 structure +
// one-iteration register software-pipeline of K/V fragments (ping-pong).

typedef unsigned short u16;
typedef unsigned int   u32;
using short8 = __attribute__((ext_vector_type(8))) short;
using f32x4  = __attribute__((ext_vector_type(4))) float;

__device__ __forceinline__ u16 f2b(float f) {
    u32 u = __float_as_uint(f);
    u += 0x7FFFu + ((u >> 16) & 1u);
    return (u16)(u >> 16);
}
__device__ __forceinline__ u32 pack2(float lo, float hi) {
    union { __hip_bfloat162 h; u32 u; } c;
    c.h = __float22bfloat162_rn(make_float2(lo, hi));
    return c.u;
}
__device__ __forceinline__ float fexp2(float x) {
    return __builtin_amdgcn_exp2f(x);
}
__device__ __forceinline__ void gld_lds16(const u16* g, u16* l) {
    __builtin_amdgcn_global_load_lds(
        (const __attribute__((address_space(1))) void*)g,
        (__attribute__((address_space(3))) void*)l, 16, 0, 0);
}

// ---------------------------------------------------------------------------
// fp32 -> bf16 convert. grid (1024, 7).
// ---------------------------------------------------------------------------
__global__ __launch_bounds__(256) void convert_kernel(
    const float* s0, const float* s1, const float* s2, const float* s3,
    const float* s4, const float* s5, const float* s6,
    u16* d0, u16* d1, u16* d2, u16* d3, u16* d4, u16* d5, u16* d6)
{
    const int y = blockIdx.y;
    const float* s; u16* d; u32 n;
    switch (y) {
        case 0: s = s0; d = d0; n = 1048576; break;
        case 1: s = s1; d = d1; n = 1048576; break;
        case 2: s = s2; d = d2; n = 1048576; break;
        case 3: s = s3; d = d3; n = 262144; break;
        case 4: s = s4; d = d4; n = 262144; break;
        case 5: s = s5; d = d5; n = 262144; break;
        default: s = s6; d = d6; n = 262144; break;
    }
    for (u32 i = blockIdx.x * 256 + threadIdx.x; i < n; i += 256 * 1024) {
        float4 f = ((const float4*)s)[i];
        uint2 o; o.x = pack2(f.x, f.y); o.y = pack2(f.z, f.w);
        ((uint2*)d)[i] = o;
    }
}

// ---------------------------------------------------------------------------
// GEMM core (round-7 proven): C(128x128) = A[m][k] @ B[n][k]^T, K=1024, bf16,
// 2-barrier global_load_lds K-loop, XOR-swizzled unpadded LDS.
// MODE 0: u16 C row-major. MODE 2: f32 C + bias. MODE 3: u16 C in Vt layout.
// ---------------------------------------------------------------------------
template <int MODE>
__device__ __forceinline__ void gemm_core(
    const u16* __restrict__ A, const u16* __restrict__ B,
    void* __restrict__ C, const float* __restrict__ bias, float scale,
    u32 bm, u32 bn)
{
    constexpr u32 K = 1024;
    __shared__ u16 As[128 * 32];
    __shared__ u16 Bs[128 * 32];

    const int tid  = threadIdx.x;
    const int lane = tid & 63;
    const int w    = tid >> 6;
    const int wr   = w >> 1, wc = w & 1;
    const int ml   = lane & 15, g = lane >> 4;

    f32x4 acc[4][4] = {};

    const u32 srow = w * 32 + (lane >> 2);
    const u32 scol = (u32)(((lane & 3) ^ ((lane >> 3) & 3)) * 8);
    const u16* gA = A + (size_t)(bm + srow) * K + scol;
    const u16* gB = B + (size_t)(bn + srow) * K + scol;
    u16* lA = &As[w * 1024];
    u16* lB = &Bs[w * 1024];

    const u32 fsw = (u32)((g ^ ((ml >> 1) & 3)) * 8);

    for (u32 k0 = 0; k0 < K; k0 += 32) {
        __syncthreads();
        gld_lds16(gA + k0, lA);
        gld_lds16(gA + 16 * K + k0, lA + 512);
        gld_lds16(gB + k0, lB);
        gld_lds16(gB + 16 * K + k0, lB + 512);
        __syncthreads();

        short8 af[4], bf[4];
#pragma unroll
        for (int it = 0; it < 4; ++it)
            af[it] = *(const short8*)&As[(wr * 64 + it * 16 + ml) * 32 + fsw];
#pragma unroll
        for (int ct = 0; ct < 4; ++ct)
            bf[ct] = *(const short8*)&Bs[(wc * 64 + ct * 16 + ml) * 32 + fsw];
#pragma unroll
        for (int it = 0; it < 4; ++it)
#pragma unroll
            for (int ct = 0; ct < 4; ++ct)
                acc[it][ct] = __builtin_amdgcn_mfma_f32_16x16x32_bf16(
                    af[it], bf[ct], acc[it][ct], 0, 0, 0);
    }

    if (MODE == 3) {
#pragma unroll
        for (int ct = 0; ct < 4; ++ct) {
            const u32 col = bn + wc * 64 + ct * 16 + ml;
            u16* dst = (u16*)C + (col >> 11) * 2097152 + (col & 2047);
#pragma unroll
            for (int it = 0; it < 4; ++it) {
                const u32 row = bm + wr * 64 + it * 16 + g * 4;
#pragma unroll
                for (int r = 0; r < 4; ++r)
                    dst[(size_t)(row + r) * 2048] = f2b(acc[it][ct][r]);
            }
        }
    } else {
#pragma unroll
        for (int ct = 0; ct < 4; ++ct) {
            const u32 col = bn + wc * 64 + ct * 16 + ml;
            const float bv = (MODE == 2 && bias) ? bias[col] : 0.0f;
#pragma unroll
            for (int it = 0; it < 4; ++it) {
                const u32 row = bm + wr * 64 + it * 16 + g * 4;
#pragma unroll
                for (int r = 0; r < 4; ++r) {
                    const float v = acc[it][ct][r] * scale + bv;
                    if (MODE == 2) ((float*)C)[(size_t)(row + r) * 1024 + col] = v;
                    else           ((u16*)C)[(size_t)(row + r) * 1024 + col] = f2b(v);
                }
            }
        }
    }
}

__global__ __launch_bounds__(256) void proj3_kernel(
    const u16* kb, const u16* qb, const u16* vb,
    const u16* Wkb, const u16* Wqb, const u16* Wvb,
    u16* Kp, u16* Qp, u16* Vt)
{
    if (blockIdx.z == 0)
        gemm_core<0>(kb, Wkb, Kp, nullptr, 1.0f, blockIdx.y * 128, blockIdx.x * 128);
    else if (blockIdx.z == 1)
        gemm_core<0>(qb, Wqb, Qp, nullptr, 0.18033688011112042f, blockIdx.y * 128, blockIdx.x * 128);
    else
        gemm_core<3>(Wvb, vb, Vt, nullptr, 1.0f, blockIdx.x * 128, blockIdx.y * 128);
}

// ---------------------------------------------------------------------------
// OUT GEMM: 64x128 tile, grid (8, 64) = 512 blocks (2/CU). Wave w: rows
// (w>>1)*32..+31, cols (w&1)*64..+63 -> acc[2][4]. Same staging/swizzle.
// ---------------------------------------------------------------------------
__global__ __launch_bounds__(256) void out_gemm_kernel(
    const u16* __restrict__ A, const u16* __restrict__ W,
    float* __restrict__ C, const float* __restrict__ bias)
{
    constexpr u32 K = 1024;
    __shared__ u16 As[64 * 32];
    __shared__ u16 Bs[128 * 32];

    const int tid  = threadIdx.x;
    const int lane = tid & 63;
    const int w    = tid >> 6;
    const int wr   = w >> 1, wc = w & 1;
    const int ml   = lane & 15, g = lane >> 4;
    const u32 bm   = blockIdx.y * 64, bn = blockIdx.x * 128;

    f32x4 acc[2][4] = {};

    const u32 scol = (u32)(((lane & 3) ^ ((lane >> 3) & 3)) * 8);
    const u16* gA = A + (size_t)(bm + w * 16 + (lane >> 2)) * K + scol;
    const u16* gB = W + (size_t)(bn + w * 32 + (lane >> 2)) * K + scol;
    u16* lA = &As[w * 512];
    u16* lB = &Bs[w * 1024];

    const u32 fsw = (u32)((g ^ ((ml >> 1) & 3)) * 8);

    for (u32 k0 = 0; k0 < K; k0 += 32) {
        __syncthreads();
        gld_lds16(gA + k0, lA);
        gld_lds16(gB + k0, lB);
        gld_lds16(gB + 16 * K + k0, lB + 512);
        __syncthreads();

        short8 af[2], bf[4];
#pragma unroll
        for (int it = 0; it < 2; ++it)
            af[it] = *(const short8*)&As[(wr * 32 + it * 16 + ml) * 32 + fsw];
#pragma unroll
        for (int ct = 0; ct < 4; ++ct)
            bf[ct] = *(const short8*)&Bs[(wc * 64 + ct * 16 + ml) * 32 + fsw];
#pragma unroll
        for (int it = 0; it < 2; ++it)
#pragma unroll
            for (int ct = 0; ct < 4; ++ct)
                acc[it][ct] = __builtin_amdgcn_mfma_f32_16x16x32_bf16(
                    af[it], bf[ct], acc[it][ct], 0, 0, 0);
    }

#pragma unroll
    for (int ct = 0; ct < 4; ++ct) {
        const u32 col = bn + wc * 64 + ct * 16 + ml;
        const float bv = bias ? bias[col] : 0.0f;
#pragma unroll
        for (int it = 0; it < 2; ++it) {
            const u32 row = bm + wr * 32 + it * 16 + g * 4;
#pragma unroll
            for (int r = 0; r < 4; ++r)
                C[(size_t)(row + r) * 1024 + col] = acc[it][ct][r] + bv;
        }
    }
}

// ---------------------------------------------------------------------------
// Flash attention v6 = round-7 structure + 1-iter register software pipeline.
// Block = (bh, 64 q), 4 waves; wave w owns s-slice w*32..+31 per 128-s iter.
// K/V/Q frags direct from global; next iter's va/ka loaded (ping-pong regs)
// before current iter's QK/exp/P/PV chain. Per-wave swizzled P strip in LDS.
// No-max softmax. Cross-wave O/l reduction at end only.
// ---------------------------------------------------------------------------
__global__ __launch_bounds__(256, 2) void attn_kernel(
    const u16* __restrict__ Qp, const u16* __restrict__ Kp,
    const u16* __restrict__ Vt, u16* __restrict__ Op)
{
    __shared__ u16   Ps[4 * 2048];
    __shared__ float R0[4096];
    __shared__ float Lr[256];

    const int tid  = threadIdx.x;
    const int lane = tid & 63;
    const int w    = tid >> 6;
    const int ml   = lane & 15;
    const int g    = lane >> 4;
    const u32 bh   = blockIdx.y;
    const u32 b    = bh >> 4, h = bh & 15;
    const u32 t0   = blockIdx.x * 64;

    const u32 base  = b * 2048 * 1024 + h * 64;
    const u32 vbase = bh * 64 * 2048;

    short8 bq[4][2];
#pragma unroll
    for (int qt = 0; qt < 4; ++qt) {
        const u16* qr = Qp + base + (t0 + qt * 16 + ml) * 1024 + g * 8;
        bq[qt][0] = *(const short8*)qr;
        bq[qt][1] = *(const short8*)(qr + 32);
    }

    f32x4 oacc[4][4] = {};
    float l4[4] = {};

    u16* Pw = &Ps[w * 2048];
    u32* Pw32 = (u32*)Pw;

    u32 kOff = base + (w * 32 + ml) * 1024 + g * 8;
    u32 vOff = vbase + ml * 2048 + w * 32 + g * 8;

    short8 va[2][4], ka[2][2][2];
    // prologue: iter 0 fragments into slot 0
#pragma unroll
    for (int dt = 0; dt < 4; ++dt)
        va[0][dt] = *(const short8*)(Vt + vOff + dt * 32768);
#pragma unroll
    for (int sub = 0; sub < 2; ++sub) {
        const u16* kp = Kp + kOff + sub * 16384;
        ka[0][sub][0] = *(const short8*)kp;
        ka[0][sub][1] = *(const short8*)(kp + 32);
    }
    kOff += 131072; vOff += 128;

#define ATTN_STEP(CUR, NXT, PREF)                                            \
    {                                                                        \
        if (PREF) {                                                          \
            _Pragma("unroll")                                                \
            for (int dt = 0; dt < 4; ++dt)                                   \
                va[NXT][dt] = *(const short8*)(Vt + vOff + dt * 32768);      \
            _Pragma("unroll")                                                \
            for (int sub = 0; sub < 2; ++sub) {                              \
                const u16* kp = Kp + kOff + sub * 16384;                     \
                ka[NXT][sub][0] = *(const short8*)kp;                        \
                ka[NXT][sub][1] = *(const short8*)(kp + 32);                 \
            }                                                                \
            kOff += 131072; vOff += 128;                                     \
        }                                                                    \
        _Pragma("unroll")                                                    \
        for (int sub = 0; sub < 2; ++sub) {                                  \
            const u32 ch = (u32)(sub * 2 + (g >> 1));                        \
            _Pragma("unroll")                                                \
            for (int qt = 0; qt < 4; ++qt) {                                 \
                f32x4 z = {};                                                \
                z = __builtin_amdgcn_mfma_f32_16x16x32_bf16(                 \
                    ka[CUR][sub][0], bq[qt][0], z, 0, 0, 0);                 \
                z = __builtin_amdgcn_mfma_f32_16x16x32_bf16(                 \
                    ka[CUR][sub][1], bq[qt][1], z, 0, 0, 0);                 \
                const float p0 = fexp2(z[0]), p1 = fexp2(z[1]);              \
                const float p2 = fexp2(z[2]), p3 = fexp2(z[3]);              \
                l4[qt] += (p0 + p1) + (p2 + p3);                             \
                const u32 q = (u32)(qt * 16 + ml);                           \
                const u32 idx = q * 16 + ((ch ^ ((q >> 1) & 3)) << 2)        \
                                + (g & 1) * 2;                               \
                uint2 pv; pv.x = pack2(p0, p1); pv.y = pack2(p2, p3);        \
                *(uint2*)&Pw32[idx] = pv;                                    \
            }                                                                \
        }                                                                    \
        short8 pb[4];                                                        \
        _Pragma("unroll")                                                    \
        for (int qt = 0; qt < 4; ++qt) {                                     \
            const u32 q = (u32)(qt * 16 + ml);                               \
            pb[qt] = *(const short8*)&Pw[q * 32 + ((g ^ ((q >> 1) & 3)) * 8)]; \
        }                                                                    \
        _Pragma("unroll")                                                    \
        for (int dt = 0; dt < 4; ++dt)                                       \
            _Pragma("unroll")                                                \
            for (int qt = 0; qt < 4; ++qt)                                   \
                oacc[dt][qt] = __builtin_amdgcn_mfma_f32_16x16x32_bf16(      \
                    va[CUR][dt], pb[qt], oacc[dt][qt], 0, 0, 0);             \
    }

    for (int it = 0; it < 7; ++it) {
        ATTN_STEP(0, 1, true)
        ATTN_STEP(1, 0, true)
    }
    ATTN_STEP(0, 1, true)
    ATTN_STEP(1, 0, false)
#undef ATTN_STEP

    // ---- cross-wave reduction ----
#pragma unroll
    for (int qt = 0; qt < 4; ++qt) {
        l4[qt] += __shfl_xor(l4[qt], 16);
        l4[qt] += __shfl_xor(l4[qt], 32);
    }
    if (g == 0) {
#pragma unroll
        for (int qt = 0; qt < 4; ++qt) Lr[w * 64 + qt * 16 + ml] = l4[qt];
    }
    __syncthreads();
    float* R1 = (float*)Ps;

#define WRITE_R(Rp)                                                          \
    {_Pragma("unroll") for (int dt = 0; dt < 4; ++dt)                        \
     _Pragma("unroll") for (int qt = 0; qt < 4; ++qt)                        \
     _Pragma("unroll") for (int r = 0; r < 4; ++r)                           \
        (Rp)[(dt * 16 + g * 4 + r) * 64 + qt * 16 + ml] = oacc[dt][qt][r];}
#define ADD_R(Rp)                                                            \
    {_Pragma("unroll") for (int dt = 0; dt < 4; ++dt)                        \
     _Pragma("unroll") for (int qt = 0; qt < 4; ++qt)                        \
     _Pragma("unroll") for (int r = 0; r < 4; ++r)                           \
        oacc[dt][qt][r] += (Rp)[(dt * 16 + g * 4 + r) * 64 + qt * 16 + ml];}

    if (w == 1) WRITE_R(R0)
    if (w == 3) WRITE_R(R1)
    __syncthreads();
    if (w == 0) ADD_R(R0)
    if (w == 2) ADD_R(R1)
    __syncthreads();
    if (w == 2) WRITE_R(R0)
    __syncthreads();
    if (w == 0) {
        ADD_R(R0)
#pragma unroll
        for (int qt = 0; qt < 4; ++qt) {
            const u32 q = (u32)(qt * 16 + ml);
            const float inv = 1.0f / (Lr[q] + Lr[64 + q] + Lr[128 + q] + Lr[192 + q]);
            const u32 row = (b * 2048 + t0 + q) * 1024 + h * 64;
#pragma unroll
            for (int dt = 0; dt < 4; ++dt) {
                const u32 ci = row + dt * 16 + g * 4;
                *(u32*)&Op[ci]     = pack2(oacc[dt][qt][0] * inv, oacc[dt][qt][1] * inv);
                *(u32*)&Op[ci + 2] = pack2(oacc[dt][qt][2] * inv, oacc[dt][qt][3] * inv);
            }
        }
    }
#undef WRITE_R
#undef ADD_R
}

extern "C" void kernel_launch(void* const* d_in, const int* in_sizes, int n_in,
                              void* d_out, int out_size, void* d_ws, size_t ws_size,
                              hipStream_t stream)
{
    const float* kin = (const float*)d_in[0];
    const float* qin = (const float*)d_in[1];
    const float* vin = (const float*)d_in[2];
    const float* Wk  = (const float*)d_in[3];
    const float* Wq  = (const float*)d_in[4];
    const float* Wv  = (const float*)d_in[5];
    const float* Wo  = (const float*)d_in[6];
    const float* bo  = (const float*)d_in[7];
    float* out = (float*)d_out;

    const size_t ACT = 4194304;
    const size_t WSZ = 1048576;

    u16* kb  = (u16*)d_ws;
    u16* qb  = kb + ACT;
    u16* vb  = qb + ACT;
    u16* Wkb = vb + ACT;
    u16* Wqb = Wkb + WSZ;
    u16* Wvb = Wqb + WSZ;
    u16* Wob = Wvb + WSZ;
    u16* Kp  = Wob + WSZ;
    u16* Qp  = Kp + ACT;
    u16* Vt  = Qp + ACT;
    u16* Op  = kb;   // alias: kb consumed by proj3 before attn writes Op

    convert_kernel<<<dim3(1024, 7), 256, 0, stream>>>(
        kin, qin, vin, Wk, Wq, Wv, Wo, kb, qb, vb, Wkb, Wqb, Wvb, Wob);
    proj3_kernel<<<dim3(8, 32, 3), 256, 0, stream>>>(
        kb, qb, vb, Wkb, Wqb, Wvb, Kp, Qp, Vt);
    attn_kernel<<<dim3(32, 32), 256, 0, stream>>>(Qp, Kp, Vt, Op);
    out_gemm_kernel<<<dim3(8, 64), 256, 0, stream>>>(Op, Wob, out, bo);
}